// Round 13
// baseline (523.180 us; speedup 1.0000x reference)
//
#include <hip/hip_runtime.h>
#include <cmath>

#pragma clang fp contract(off)

typedef unsigned long long ull;
typedef unsigned int uint;

#define NPRIORS 131072
#define NIMG 16
#define KSEL 5000
#define TOPK 750
#define SORTN 8192
#define MW 80                      // mask words per row (640 B, 16B-aligned)
#define NCHUNK 79
#define KSELP (NCHUNK * 64)        // 5056
#define NBIN 65536

// Exact midpoint between 0.3f and nextafterf(0.3f): fl32(inter/u) > 0.3f
// <=> (double)inter > MID03 * (double)uni  (25b x 24b product exact in double;
// tie at midpoint rounds to even mantissa = 0.3f, i.e. NOT >).
#define MID03 0.30000002682209014892578125

// ---------------- workspace layout ----------------
#define WS_PAIRS 0                                   // u64 [16][8192]   1 MB
#define WS_NDIAG 0                                   // u64 [16][KSELP] (aliased)
#define WS_MCNT 1048576                              // int [64]
#define WS_BOXES 1048832                             // f4  [16][5000]
#define WS_SCORES 2328832                            // f32 [16][5000]
#define WS_MASK 2649088                              // u64 [16][5000][80]  51.2 MB
#define WS_HIST (WS_MASK)                            // u32 [16][65536] (aliased, pre-mask)
#define WS_CNT  (WS_MASK + 4194304)                  // u32 [16][65536] (zeroed by cutoff)
#define WS_POS  (WS_MASK + 8388608)                  // u32 [16][65536] (no memset needed)
#define WS_DIAG (WS_MASK + (size_t)NIMG * KSEL * MW * 8)   // 53,849,088

__device__ inline ull readlane64(ull t, int l) {
  unsigned lo = (unsigned)__builtin_amdgcn_readlane((int)(unsigned)t, l);
  unsigned hi = (unsigned)__builtin_amdgcn_readlane((int)(unsigned)(t >> 32), l);
  return ((ull)hi << 32) | lo;
}

__device__ __forceinline__ ull rfl64(ull t) {
  unsigned lo = (unsigned)__builtin_amdgcn_readfirstlane((int)(unsigned)t);
  unsigned hi = (unsigned)__builtin_amdgcn_readfirstlane((int)(unsigned)(t >> 32));
  return ((ull)hi << 32) | lo;
}

// workgroup barrier WITHOUT the vmcnt(0) drain __syncthreads carries.
__device__ inline void softBarrier() {
  asm volatile("s_waitcnt lgkmcnt(0)\n\ts_barrier" ::: "memory");
}

// ============ Kernel 1: histogram on bin = (bits>>12)&0xFFFF ============
__global__ __launch_bounds__(256) void hist_kernel(const float* __restrict__ conf,
                                                   unsigned int* __restrict__ hist) {
  const int img = blockIdx.y;
  const float4* c4 = (const float4*)conf + (size_t)img * (NPRIORS / 2);
  unsigned int* H = hist + (size_t)img * NBIN;
  for (int q = blockIdx.x * 256 + threadIdx.x; q < NPRIORS / 2; q += 64 * 256) {
    float4 v = c4[q];
    if (v.y > 0.05f) atomicAdd(&H[(__float_as_uint(v.y) >> 12) & 0xFFFFu], 1u);
    if (v.w > 0.05f) atomicAdd(&H[(__float_as_uint(v.w) >> 12) & 0xFFFFu], 1u);
  }
}

// ============ Kernel 2: coalesced chunk-sum scan -> cutoff + bin bases ============
// also zeroes cnt[b] for all bins b >= cc*64 — exactly the set scatter touches.
__global__ __launch_bounds__(1024) void cutoff_kernel(const unsigned int* __restrict__ hist,
                                                      unsigned int* __restrict__ pos,
                                                      unsigned int* __restrict__ cnt,
                                                      int* __restrict__ meta,
                                                      float4* __restrict__ sboxes,
                                                      float* __restrict__ sscores) {
  const int img = blockIdx.x;
  const int tid = threadIdx.x;
  const int lane = tid & 63;
  const int wv = tid >> 6;
  const unsigned int* H = hist + (size_t)img * NBIN;
  unsigned int* P = pos + (size_t)img * NBIN;
  unsigned int* Cn = cnt + (size_t)img * NBIN;
  __shared__ unsigned int csum[1024];
  __shared__ unsigned int suf[1024];
  __shared__ int s_cc;
  __shared__ unsigned int s_cut, s_mc;

  for (int g = 0; g < 64; ++g) {
    unsigned int v = H[g * 1024 + tid];
    for (int m = 1; m < 64; m <<= 1) v += __shfl_xor(v, m);
    if (lane == 0) csum[g * 16 + wv] = v;
  }
  __syncthreads();
  suf[tid] = csum[tid];
  if (tid == 0) s_cc = 0;
  __syncthreads();
  for (int off = 1; off < 1024; off <<= 1) {
    unsigned int v = (tid + off < 1024) ? suf[tid + off] : 0u;
    __syncthreads();
    suf[tid] += v;
    __syncthreads();
  }
  if (suf[tid] >= KSEL && (suf[tid] - csum[tid]) < KSEL) s_cc = tid;  // unique
  __syncthreads();
  const int cc = s_cc;
  if (tid == 0) { s_cut = (unsigned int)(cc * 64); s_mc = suf[0]; }
  __syncthreads();
  for (int b = cc * 64 + tid; b < NBIN; b += 1024) {
    int q = b >> 6;
    unsigned int acc = (q + 1 < 1024) ? suf[q + 1] : 0u;
    for (int b2 = b + 1; b2 < (q + 1) * 64; ++b2) acc += H[b2];
    P[b] = acc;
    Cn[b] = 0u;
    unsigned int h = H[b];
    if (acc < KSEL && acc + h >= KSEL) { s_cut = (unsigned int)b; s_mc = acc + h; }
  }
  __syncthreads();
  if (tid == 0) {
    meta[img] = (int)min(s_mc, (unsigned int)SORTN);
    meta[16 + img] = (int)s_cut;
  }
  for (int i = tid; i < KSEL; i += 1024) {
    sboxes[(size_t)img * KSEL + i] = make_float4(0.f, 0.f, 0.f, 0.f);
    sscores[(size_t)img * KSEL + i] = -1e9f;
  }
}

// ============ Kernel 3: scatter candidates to bin-grouped slots ============
__global__ __launch_bounds__(256) void scatter_kernel(const float* __restrict__ conf,
                                                      const unsigned int* __restrict__ pos,
                                                      unsigned int* __restrict__ cnt,
                                                      const int* __restrict__ meta,
                                                      ull* __restrict__ pairs) {
  const int img = blockIdx.y;
  const float4* c4 = (const float4*)conf + (size_t)img * (NPRIORS / 2);
  const unsigned int* P = pos + (size_t)img * NBIN;
  unsigned int* Cn = cnt + (size_t)img * NBIN;
  ull* mypairs = pairs + (size_t)img * SORTN;
  const unsigned int cutval = ((unsigned int)meta[16 + img]) << 12;
  for (int q = blockIdx.x * 256 + threadIdx.x; q < NPRIORS / 2; q += 64 * 256) {
    float4 v = c4[q];
#pragma unroll
    for (int h = 0; h < 2; ++h) {
      float sc = h ? v.w : v.y;
      unsigned int p = 2 * (unsigned int)q + h;
      if (sc > 0.05f) {
        unsigned int u = __float_as_uint(sc);
        if (u >= cutval) {
          unsigned int bin = (u >> 12) & 0xFFFFu;
          unsigned int slot = atomicAdd(&Cn[bin], 1u);
          unsigned int idx = P[bin] + slot;
          if (idx < SORTN)
            mypairs[idx] = ((ull)u << 32) | (ull)(0xFFFFFFFFu - p);
        }
      }
    }
  }
}

// ============ Kernel 4: rank within bin (exact order) + SSD decode ============
__global__ __launch_bounds__(256) void rank_decode_kernel(const ull* __restrict__ pairs,
                                                          const unsigned int* __restrict__ hist,
                                                          const unsigned int* __restrict__ pos,
                                                          const int* __restrict__ meta,
                                                          const float* __restrict__ loc,
                                                          const float* __restrict__ prior,
                                                          float4* __restrict__ sboxes,
                                                          float* __restrict__ sscores) {
#pragma clang fp contract(off)
  const int img = blockIdx.y;
  const int s = blockIdx.x * 256 + threadIdx.x;
  const int mc = meta[img];
  if (s >= mc) return;
  const ull* mypairs = pairs + (size_t)img * SORTN;
  const ull key = mypairs[s];
  const unsigned int u = (unsigned int)(key >> 32);
  const unsigned int bin = (u >> 12) & 0xFFFFu;
  const unsigned int base = pos[(size_t)img * NBIN + bin];
  const unsigned int cb = hist[(size_t)img * NBIN + bin];
  const int end = min((int)(base + cb), mc);
  int rank = 0;
  for (int j = (int)base; j < end; ++j) rank += (mypairs[j] > key);
  const int fp = (int)base + rank;
  if (fp >= KSEL) return;
  const unsigned int p = 0xFFFFFFFFu - (unsigned int)(key & 0xFFFFFFFFu);
  const float* lp = loc + ((size_t)img * NPRIORS + p) * 4;
  const float* pp = prior + (size_t)p * 4;
  float l0 = lp[0], l1 = lp[1], l2 = lp[2], l3 = lp[3];
  float px = pp[0], py = pp[1], pw = pp[2], ph = pp[3];
  float cx = px + (l0 * 0.1f) * pw;
  float cy = py + (l1 * 0.1f) * ph;
  float w = pw * (float)exp((double)(l2 * 0.2f));
  float hh = ph * (float)exp((double)(l3 * 0.2f));
  float4 box;
  box.x = cx - w * 0.5f;
  box.y = cy - hh * 0.5f;
  box.z = cx + w * 0.5f;
  box.w = cy + hh * 0.5f;
  sboxes[(size_t)img * KSEL + fp] = box;
  sscores[(size_t)img * KSEL + fp] = __uint_as_float(u);
}

// ============ Kernel 5: IoU mask build — TRANSPOSED + BATCHED ============
// v13: lane = row (R8's verified layout), columns serial — but the two R8
//   latency killers are fixed:
//   (a) columns processed in batches of 8: 10 independent LDS loads up
//       front, then 8 pure-VALU column bodies (no per-column load stall);
//   (b) the exactness check is hoisted out of the inner loop: per column
//       only amb |= __ballot(|f|<=band) (v_cmp->SGPR + s_or, off the VALU
//       chain); tested ONCE per 64-col word. Rare slow path (~4e-4/word)
//       recomputes the whole word with the exact f64 midpoint predicate —
//       bit-identical decisions.
// diag[i]  = row i's word chunk(i), masked to cols > i (per-lane mlo/mhi)
// ndiag[i] = row i's word chunk(i)+1, raw: (jt==rt, wv<3) word wv+1, or
//   (jt==rt+1, wv==3) word 0. Sub-diagonal mask-word content is don't-care
//   for the sweep (published words always exceed the picks' own chunks).
__global__ __launch_bounds__(256) void mask_build_kernel(const float4* __restrict__ sboxes,
                                                         ull* __restrict__ mask,
                                                         ull* __restrict__ diag,
                                                         ull* __restrict__ ndiag) {
#pragma clang fp contract(off)
  const int jt = blockIdx.x;       // col tile (256 cols)
  const int rt = blockIdx.y;       // row tile (256 rows)
  const int img = blockIdx.z;
  if (jt < rt) return;             // fully sub-diagonal tile
  const int tid = threadIdx.x;
  const int lane = tid & 63;
  const int wv = __builtin_amdgcn_readfirstlane(tid >> 6);  // provably uniform
  const float4* bb = sboxes + (size_t)img * KSEL;

  __shared__ float4 cbox[256];
  __shared__ float carea[256];
  {
    int j = jt * 256 + tid;
    float4 c = (j < KSEL) ? bb[j] : make_float4(0.f, 0.f, 0.f, 0.f);
    cbox[tid] = c;
    carea[tid] = (c.z - c.x) * (c.w - c.y);
  }
  __syncthreads();

  const int R = rt * 256 + wv * 64;     // wave's row base (64-aligned)
  if (R >= KSEL) return;                // whole wave beyond rows (rt=19, wv=3)
  const int i = R + lane;               // this lane's row
  float4 pb = (i < KSEL) ? bb[i] : make_float4(0.f, 0.f, 0.f, 0.f);
  const float pa = (pb.z - pb.x) * (pb.w - pb.y);

  uint wl[4], wh[4];
#pragma unroll
  for (int s = 0; s < 4; ++s) {
    // skip fully sub-diagonal words of the diagonal tile
    if (jt == rt && s < wv) { wl[s] = 0u; wh[s] = 0u; continue; }
    uint alo = 0, ahi = 0;
    ull amb = 0ULL;                      // SGPR accumulator (uniform)
#pragma unroll
    for (int b8 = 0; b8 < 8; ++b8) {
      const int j0 = s * 64 + b8 * 8;
      float4 c[8];
      float a[8];
#pragma unroll
      for (int u = 0; u < 8; ++u) c[u] = cbox[j0 + u];
      {
        float4 a03 = *(const float4*)&carea[j0];
        float4 a47 = *(const float4*)&carea[j0 + 4];
        a[0] = a03.x; a[1] = a03.y; a[2] = a03.z; a[3] = a03.w;
        a[4] = a47.x; a[5] = a47.y; a[6] = a47.z; a[7] = a47.w;
      }
      uint bacc = 0;
#pragma unroll
      for (int u = 0; u < 8; ++u) {
        float ltx = fmaxf(pb.x, c[u].x), lty = fmaxf(pb.y, c[u].y);
        float rbx = fminf(pb.z, c[u].z), rby = fminf(pb.w, c[u].w);
        float ww = fmaxf(rbx - ltx, 0.0f), hh = fmaxf(rby - lty, 0.0f);
        float inter = ww * hh;
        float uni = fmaxf(pa + a[u] - inter, 1e-12f);
        float f = fmaf(-0.3f, uni, inter);
        float band = uni * 0x1p-20f;
        bacc |= (f > band) ? (1u << u) : 0u;
        amb |= __ballot(fabsf(f) <= band);   // v_cmp->sgpr + s_or (cheap)
      }
      if (b8 < 4) alo |= bacc << (b8 * 8);
      else        ahi |= bacc << (b8 * 8 - 32);
    }
    if (__builtin_expect(amb != 0ULL, 0)) {   // wave-uniform, ~never taken
      asm volatile("" ::: "memory");          // body must NOT be speculated
      alo = 0; ahi = 0;
      for (int b = 0; b < 64; ++b) {
        float4 c = cbox[s * 64 + b];
        float aa = carea[s * 64 + b];
        float ltx = fmaxf(pb.x, c.x), lty = fmaxf(pb.y, c.y);
        float rbx = fminf(pb.z, c.z), rby = fminf(pb.w, c.w);
        float ww = fmaxf(rbx - ltx, 0.0f), hh = fmaxf(rby - lty, 0.0f);
        float inter = ww * hh;
        float uni = fmaxf(pa + aa - inter, 1e-12f);
        bool kill = (double)inter > MID03 * (double)uni;   // exact predicate
        if (b < 32) alo |= (kill ? 1u : 0u) << b;
        else        ahi |= (kill ? 1u : 0u) << (b - 32);
      }
    }
    wl[s] = alo; wh[s] = ahi;
  }

  if (jt == rt) {
    // per-lane mask of columns strictly AFTER this row within its own chunk
    uint mlo, mhi;
    if (lane < 32) { mlo = 0xFFFFFFFEu << lane; mhi = 0xFFFFFFFFu; }
    else           { mlo = 0u; mhi = 0xFFFFFFFEu << (lane - 32); }
    uint dl, dh;
    if (wv == 0)      { wl[0] &= mlo; wh[0] &= mhi; dl = wl[0]; dh = wh[0]; }
    else if (wv == 1) { wl[1] &= mlo; wh[1] &= mhi; dl = wl[1]; dh = wh[1]; }
    else if (wv == 2) { wl[2] &= mlo; wh[2] &= mhi; dl = wl[2]; dh = wh[2]; }
    else              { wl[3] &= mlo; wh[3] &= mhi; dl = wl[3]; dh = wh[3]; }
    if (i < KSEL) {
      diag[(size_t)img * KSELP + i] = ((ull)dh << 32) | dl;
      if (wv < 3) {
        uint nl, nh;
        if (wv == 0)      { nl = wl[1]; nh = wh[1]; }
        else if (wv == 1) { nl = wl[2]; nh = wh[2]; }
        else              { nl = wl[3]; nh = wh[3]; }
        ndiag[(size_t)img * KSELP + i] = ((ull)nh << 32) | nl;
      }
    }
  }
  if (jt == rt + 1 && wv == 3 && i < KSEL)
    ndiag[(size_t)img * KSELP + i] = ((ull)wh[0] << 32) | wl[0];

  if (i < KSEL) {
    uint* wp = (uint*)(mask + (size_t)img * KSEL * MW + (size_t)i * MW) + jt * 8;
    *(uint4*)wp = make_uint4(wl[0], wh[0], wl[1], wh[1]);
    *((uint4*)wp + 1) = make_uint4(wl[2], wh[2], wl[3], wh[3]);
  }
}

// ============ Kernel 6: sweep — producer/consumer wave pair (R10/R12) ============
// Scalarized walker (SGPR s_ff1 chain, mbcnt-ranked pickbuf, 2-deep diag
// prefetch) + full-output epilogue (replaces host memset of d_out).
__global__ __launch_bounds__(128) void sweep_kernel(const ull* __restrict__ mask,
                                                    const ull* __restrict__ diag,
                                                    const ull* __restrict__ ndiag,
                                                    const float4* __restrict__ sboxes,
                                                    const float* __restrict__ sscores,
                                                    const int* __restrict__ meta,
                                                    float* __restrict__ out) {
  const int img = blockIdx.x;
  const int tid = threadIdx.x;
  const int lane = tid & 63;
  const bool waveA = (tid < 64);
  const int V = min(meta[img], KSEL);
  const ull* mb = mask + (size_t)img * KSEL * MW;
  const ull* dg = diag + (size_t)img * KSELP;
  const ull* ng = ndiag + (size_t)img * KSELP;
  __shared__ ull mailbox[NCHUNK + 1];
  __shared__ int pickbuf[TOPK];
  __shared__ int s_np[NCHUNK];
  __shared__ int s_start[NCHUNK];
  __shared__ int s_done;
  __shared__ int s_n;
  const int lc = min(lane, 39);  // B: lane-owned remv words {2lc, 2lc+1}

  for (int i = tid; i <= NCHUNK; i += 128) mailbox[i] = 0ULL;
  if (tid == 0) { s_done = 0; s_n = 0; }
  __syncthreads();

  if (V > 0) {
    ull dw = 0, ndw = 0, dw1 = 0, ndw1 = 0, bridge = 0;  // A (2-deep prefetch)
    ull rlo = 0, rhi = 0;                                // B
    int nkeep = 0;
    bool adone = false;
    if (waveA) {
      dw = dg[lane]; ndw = ng[lane];
      const int i1 = min(64 + lane, KSELP - 1);
      dw1 = dg[i1]; ndw1 = ng[i1];
    }

    for (int k = 0; k < NCHUNK; ++k) {
      softBarrier();
      if (s_done) break;
      if (waveA) {
        if (!adone) {
          const int base = k * 64;
          const int nidx = min(base + 128 + lane, KSELP - 1);
          ull dw2 = dg[nidx];
          ull ndw2 = ng[nidx];
          ull cur = rfl64(mailbox[k] | bridge);
          bridge = 0ULL;
          const int lim = V - base;
          ull validm = (lim >= 64) ? ~0ULL : ((~0ULL) >> (64 - lim));
          ull avail = (~cur) & validm;
          ull picked = 0ULL;
          const int st = nkeep;
          while (avail != 0ULL && nkeep < TOPK) {
            int r = __builtin_ctzll(avail);        // s_ff1 (uniform)
            picked |= (1ULL << r);
            nkeep++;
            ull dr = readlane64(dw, r);            // critical chain
            bridge |= readlane64(ndw, r);          // off-chain
            avail &= ~(dr | (1ULL << r));
          }
          {
            uint plo = (uint)picked, phi = (uint)(picked >> 32);
            int rank = (int)__builtin_amdgcn_mbcnt_hi(
                phi, __builtin_amdgcn_mbcnt_lo(plo, 0u));
            if ((picked >> lane) & 1ULL) pickbuf[st + rank] = base + lane;
          }
          if (lane == 0) { s_np[k] = nkeep - st; s_start[k] = st; }
          if (nkeep >= TOPK || base + 64 >= V) {
            if (lane == 0) { s_done = 1; s_n = (nkeep < TOPK) ? nkeep : TOPK; }
            adone = true;
          }
          dw = dw1; ndw = ndw1;
          dw1 = dw2; ndw1 = ndw2;
        }
      } else if (k >= 1) {
        const int np = s_np[k - 1];
        const int st = s_start[k - 1];
        for (int g = 0; g < np; g += 16) {
          ulonglong2 v[16];
#pragma unroll
          for (int q = 0; q < 16; ++q) {
            int t = min(g + q, np - 1);       // clamped duplicates: idempotent OR
            int row = pickbuf[st + t];
            v[q] = *(const ulonglong2*)(mb + (size_t)row * MW + 2 * lc);
          }
#pragma unroll
          for (int q = 0; q < 16; ++q) { rlo |= v[q].x; rhi |= v[q].y; }
        }
        const int w = k + 1;
        if (w < NCHUNK) {
          ull t = (w & 1) ? rhi : rlo;
          ull word = readlane64(t, w >> 1);
          if (lane == 0) mailbox[w] = word;
        }
      }
    }
  }

  __syncthreads();
  const int n = s_n;
  float* obase = out + (size_t)img * (2 * TOPK * 5);
  for (int j = tid; j < TOPK * 5; j += 128) obase[j] = 0.f;
  for (int j = TOPK * 5 + n * 5 + tid; j < 2 * TOPK * 5; j += 128) obase[j] = 0.f;
  float* ob = obase + TOPK * 5;
  for (int j = tid; j < n; j += 128) {
    int i = pickbuf[j];
    float4 b = sboxes[(size_t)img * KSEL + i];
    float sc = sscores[(size_t)img * KSEL + i];
    float* o = ob + (size_t)j * 5;
    o[0] = sc; o[1] = b.x; o[2] = b.y; o[3] = b.z; o[4] = b.w;
  }
}

extern "C" void kernel_launch(void* const* d_in, const int* in_sizes, int n_in,
                              void* d_out, int out_size, void* d_ws, size_t ws_size,
                              hipStream_t stream) {
  const float* loc = (const float*)d_in[0];    // [16, 131072, 4]
  const float* conf = (const float*)d_in[1];   // [16*131072, 2]
  const float* prior = (const float*)d_in[2];  // [131072, 4]
  float* out = (float*)d_out;                  // [16, 2, 750, 5]

  char* ws = (char*)d_ws;
  ull* pairs = (ull*)(ws + WS_PAIRS);
  ull* ndiag = (ull*)(ws + WS_NDIAG);          // aliases pairs (dead after rank_decode)
  int* meta = (int*)(ws + WS_MCNT);
  float4* sboxes = (float4*)(ws + WS_BOXES);
  float* sscores = (float*)(ws + WS_SCORES);
  ull* mask = (ull*)(ws + WS_MASK);
  ull* diag = (ull*)(ws + WS_DIAG);
  unsigned int* hist = (unsigned int*)(ws + WS_HIST);
  unsigned int* cnt = (unsigned int*)(ws + WS_CNT);
  unsigned int* pos = (unsigned int*)(ws + WS_POS);

  // hist only (4 MB): cnt is zeroed by cutoff_kernel, out by sweep_kernel
  hipMemsetAsync(ws + WS_HIST, 0, 4194304u, stream);

  {
    dim3 g(64, NIMG);
    hist_kernel<<<g, 256, 0, stream>>>(conf, hist);
  }
  cutoff_kernel<<<NIMG, 1024, 0, stream>>>(hist, pos, cnt, meta, sboxes, sscores);
  {
    dim3 g(64, NIMG);
    scatter_kernel<<<g, 256, 0, stream>>>(conf, pos, cnt, meta, pairs);
  }
  {
    dim3 g((SORTN + 255) / 256, NIMG);
    rank_decode_kernel<<<g, 256, 0, stream>>>(pairs, hist, pos, meta, loc, prior, sboxes, sscores);
  }
  {
    dim3 g(20, 20, NIMG);
    mask_build_kernel<<<g, 256, 0, stream>>>(sboxes, mask, diag, ndiag);
  }
  sweep_kernel<<<NIMG, 128, 0, stream>>>(mask, diag, ndiag, sboxes, sscores, meta, out);
}

// Round 14
// 502.377 us; speedup vs baseline: 1.0414x; 1.0414x over previous
//
#include <hip/hip_runtime.h>
#include <cmath>

#pragma clang fp contract(off)

typedef unsigned long long ull;
typedef unsigned int uint;

#define NPRIORS 131072
#define NIMG 16
#define KSEL 5000
#define TOPK 750
#define SORTN 8192
#define MW 80                      // mask words per row (640 B, 16B-aligned)
#define NCHUNK 79
#define KSELP (NCHUNK * 64)        // 5056
#define NBIN 65536

// Exact midpoint between 0.3f and nextafterf(0.3f): fl32(inter/u) > 0.3f
// <=> (double)inter > MID03 * (double)uni  (25b x 24b product exact in double;
// tie at midpoint rounds to even mantissa = 0.3f, i.e. NOT >).
#define MID03 0.30000002682209014892578125

// ---------------- workspace layout ----------------
// ndiag aliases the pairs region: pairs are dead once rank_decode completes,
// before mask_build writes ndiag. (647 KB <= 1 MB.)
#define WS_PAIRS 0                                   // u64 [16][8192]   1 MB
#define WS_NDIAG 0                                   // u64 [16][KSELP] (aliased)
#define WS_MCNT 1048576                              // int [64]
#define WS_BOXES 1048832                              // f4  [16][5000]
#define WS_SCORES 2328832                            // f32 [16][5000]
#define WS_MASK 2649088                              // u64 [16][5000][80]  51.2 MB
#define WS_HIST (WS_MASK)                            // u32 [16][65536] (aliased, pre-mask)
#define WS_CNT  (WS_MASK + 4194304)                  // u32 [16][65536] (zeroed by cutoff)
#define WS_POS  (WS_MASK + 8388608)                  // u32 [16][65536] (no memset needed)
#define WS_DIAG (WS_MASK + (size_t)NIMG * KSEL * MW * 8)   // 53,849,088

__device__ inline ull readlane64(ull t, int l) {
  unsigned lo = (unsigned)__builtin_amdgcn_readlane((int)(unsigned)t, l);
  unsigned hi = (unsigned)__builtin_amdgcn_readlane((int)(unsigned)(t >> 32), l);
  return ((ull)hi << 32) | lo;
}

// Force a (wave-uniform) 64-bit value into SGPRs: downstream ops become
// SALU (s_ff1/s_andn2/s_or) instead of 64-bit VALU emulation. Critical for
// the sweep walker's per-pick dependency chain.
__device__ __forceinline__ ull rfl64(ull t) {
  unsigned lo = (unsigned)__builtin_amdgcn_readfirstlane((int)(unsigned)t);
  unsigned hi = (unsigned)__builtin_amdgcn_readfirstlane((int)(unsigned)(t >> 32));
  return ((ull)hi << 32) | lo;
}

// workgroup barrier WITHOUT the vmcnt(0) drain __syncthreads carries:
// LDS traffic is ordered (lgkmcnt), in-flight global loads stay in flight.
__device__ inline void softBarrier() {
  asm volatile("s_waitcnt lgkmcnt(0)\n\ts_barrier" ::: "memory");
}

// Exact "fl32(inter/uni) > 0.3f" as a 64-lane MASK — no per-lane bools.
// f = RN(inter - 0.3f*uni) (one rounding, fmaf); band = uni*2^-20 (exact).
//   f >  band  ==> kill certain      (x' = inter - MID03*uni > 0)
//   f < -band  ==> no-kill certain
//   |f|<= band ==> ambiguous (~1e-7 of pairs): wave-UNIFORM branch recomputes
//                  the exact f64 compare for all lanes and blends masks with
//                  scalar ops. Bit-identical decisions to the pure f64 path.
// The fallback body carries asm volatile("" ::: "memory") so the compiler
// cannot speculate/if-convert the f64 block into the hot path.
__device__ __forceinline__ ull kill_mask(const float4 pb, const float pa,
                                         const float4 c, const float ca2) {
  float ltx = fmaxf(pb.x, c.x), lty = fmaxf(pb.y, c.y);
  float rbx = fminf(pb.z, c.z), rby = fminf(pb.w, c.w);
  float ww = fmaxf(rbx - ltx, 0.0f), hh = fmaxf(rby - lty, 0.0f);
  float inter = ww * hh;
  float uni = fmaxf(pa + ca2 - inter, 1e-12f);
  float f = fmaf(-0.3f, uni, inter);
  float band = uni * 0x1p-20f;
  ull wfast = __ballot(f > band);
  ull wamb = __ballot(fabsf(f) <= band);
  if (__builtin_expect(wamb != 0ULL, 0)) {   // wave-uniform, ~never taken
    asm volatile("" ::: "memory");           // body must NOT be speculated
    ull wex = __ballot((double)inter > MID03 * (double)uni);
    wfast = (wfast & ~wamb) | (wex & wamb);
  }
  return wfast;
}

// ============ Kernel 1: histogram on bin = (bits>>12)&0xFFFF ============
__global__ __launch_bounds__(256) void hist_kernel(const float* __restrict__ conf,
                                                   unsigned int* __restrict__ hist) {
  const int img = blockIdx.y;
  const float4* c4 = (const float4*)conf + (size_t)img * (NPRIORS / 2);
  unsigned int* H = hist + (size_t)img * NBIN;
  for (int q = blockIdx.x * 256 + threadIdx.x; q < NPRIORS / 2; q += 64 * 256) {
    float4 v = c4[q];
    if (v.y > 0.05f) atomicAdd(&H[(__float_as_uint(v.y) >> 12) & 0xFFFFu], 1u);
    if (v.w > 0.05f) atomicAdd(&H[(__float_as_uint(v.w) >> 12) & 0xFFFFu], 1u);
  }
}

// ============ Kernel 2: coalesced chunk-sum scan -> cutoff + bin bases ============
// v12: also zeroes cnt[b] for all bins b >= cc*64 — exactly the set scatter
// can touch (scatter increments cnt[bin] only for bin >= s_cut >= cc*64;
// degenerate cc==0 zeroes the whole table). Removes cnt from the host memset.
__global__ __launch_bounds__(1024) void cutoff_kernel(const unsigned int* __restrict__ hist,
                                                      unsigned int* __restrict__ pos,
                                                      unsigned int* __restrict__ cnt,
                                                      int* __restrict__ meta,
                                                      float4* __restrict__ sboxes,
                                                      float* __restrict__ sscores) {
  const int img = blockIdx.x;
  const int tid = threadIdx.x;
  const int lane = tid & 63;
  const int wv = tid >> 6;
  const unsigned int* H = hist + (size_t)img * NBIN;
  unsigned int* P = pos + (size_t)img * NBIN;
  unsigned int* Cn = cnt + (size_t)img * NBIN;
  __shared__ unsigned int csum[1024];
  __shared__ unsigned int suf[1024];
  __shared__ int s_cc;
  __shared__ unsigned int s_cut, s_mc;

  // phase 1: chunk sums (chunk = 64 consecutive bins) via coalesced tiles
  for (int g = 0; g < 64; ++g) {
    unsigned int v = H[g * 1024 + tid];
    for (int m = 1; m < 64; m <<= 1) v += __shfl_xor(v, m);
    if (lane == 0) csum[g * 16 + wv] = v;
  }
  __syncthreads();
  // phase 2: inclusive suffix scan over 1024 chunks
  suf[tid] = csum[tid];
  if (tid == 0) s_cc = 0;
  __syncthreads();
  for (int off = 1; off < 1024; off <<= 1) {
    unsigned int v = (tid + off < 1024) ? suf[tid + off] : 0u;
    __syncthreads();
    suf[tid] += v;
    __syncthreads();
  }
  if (suf[tid] >= KSEL && (suf[tid] - csum[tid]) < KSEL) s_cc = tid;  // unique
  __syncthreads();
  const int cc = s_cc;
  if (tid == 0) { s_cut = (unsigned int)(cc * 64); s_mc = suf[0]; }  // degenerate default
  __syncthreads();
  // phase 3: per-bin exclusive-suffix bases for bins >= cc*64 only (+ cnt zero)
  for (int b = cc * 64 + tid; b < NBIN; b += 1024) {
    int q = b >> 6;
    unsigned int acc = (q + 1 < 1024) ? suf[q + 1] : 0u;
    for (int b2 = b + 1; b2 < (q + 1) * 64; ++b2) acc += H[b2];
    P[b] = acc;
    Cn[b] = 0u;
    unsigned int h = H[b];
    if (acc < KSEL && acc + h >= KSEL) { s_cut = (unsigned int)b; s_mc = acc + h; }  // unique
  }
  __syncthreads();
  if (tid == 0) {
    meta[img] = (int)min(s_mc, (unsigned int)SORTN);
    meta[16 + img] = (int)s_cut;
  }
  // default fill (overwritten by rank_decode for real slots)
  for (int i = tid; i < KSEL; i += 1024) {
    sboxes[(size_t)img * KSEL + i] = make_float4(0.f, 0.f, 0.f, 0.f);
    sscores[(size_t)img * KSEL + i] = -1e9f;
  }
}

// ============ Kernel 3: scatter candidates to bin-grouped slots ============
__global__ __launch_bounds__(256) void scatter_kernel(const float* __restrict__ conf,
                                                      const unsigned int* __restrict__ pos,
                                                      unsigned int* __restrict__ cnt,
                                                      const int* __restrict__ meta,
                                                      ull* __restrict__ pairs) {
  const int img = blockIdx.y;
  const float4* c4 = (const float4*)conf + (size_t)img * (NPRIORS / 2);
  const unsigned int* P = pos + (size_t)img * NBIN;
  unsigned int* Cn = cnt + (size_t)img * NBIN;
  ull* mypairs = pairs + (size_t)img * SORTN;
  const unsigned int cutval = ((unsigned int)meta[16 + img]) << 12;
  for (int q = blockIdx.x * 256 + threadIdx.x; q < NPRIORS / 2; q += 64 * 256) {
    float4 v = c4[q];
#pragma unroll
    for (int h = 0; h < 2; ++h) {
      float sc = h ? v.w : v.y;
      unsigned int p = 2 * (unsigned int)q + h;
      if (sc > 0.05f) {
        unsigned int u = __float_as_uint(sc);
        if (u >= cutval) {
          unsigned int bin = (u >> 12) & 0xFFFFu;
          unsigned int slot = atomicAdd(&Cn[bin], 1u);
          unsigned int idx = P[bin] + slot;
          if (idx < SORTN)
            mypairs[idx] = ((ull)u << 32) | (ull)(0xFFFFFFFFu - p);
        }
      }
    }
  }
}

// ============ Kernel 4: rank within bin (exact order) + SSD decode ============
__global__ __launch_bounds__(256) void rank_decode_kernel(const ull* __restrict__ pairs,
                                                          const unsigned int* __restrict__ hist,
                                                          const unsigned int* __restrict__ pos,
                                                          const int* __restrict__ meta,
                                                          const float* __restrict__ loc,
                                                          const float* __restrict__ prior,
                                                          float4* __restrict__ sboxes,
                                                          float* __restrict__ sscores) {
#pragma clang fp contract(off)
  const int img = blockIdx.y;
  const int s = blockIdx.x * 256 + threadIdx.x;
  const int mc = meta[img];
  if (s >= mc) return;
  const ull* mypairs = pairs + (size_t)img * SORTN;
  const ull key = mypairs[s];
  const unsigned int u = (unsigned int)(key >> 32);
  const unsigned int bin = (u >> 12) & 0xFFFFu;
  const unsigned int base = pos[(size_t)img * NBIN + bin];
  const unsigned int cb = hist[(size_t)img * NBIN + bin];
  const int end = min((int)(base + cb), mc);
  int rank = 0;
  for (int j = (int)base; j < end; ++j) rank += (mypairs[j] > key);
  const int fp = (int)base + rank;
  if (fp >= KSEL) return;
  const unsigned int p = 0xFFFFFFFFu - (unsigned int)(key & 0xFFFFFFFFu);
  const float* lp = loc + ((size_t)img * NPRIORS + p) * 4;
  const float* pp = prior + (size_t)p * 4;
  float l0 = lp[0], l1 = lp[1], l2 = lp[2], l3 = lp[3];
  float px = pp[0], py = pp[1], pw = pp[2], ph = pp[3];
  float cx = px + (l0 * 0.1f) * pw;
  float cy = py + (l1 * 0.1f) * ph;
  float w = pw * (float)exp((double)(l2 * 0.2f));
  float hh = ph * (float)exp((double)(l3 * 0.2f));
  float4 box;
  box.x = cx - w * 0.5f;
  box.y = cy - hh * 0.5f;
  box.z = cx + w * 0.5f;
  box.w = cy + hh * 0.5f;
  sboxes[(size_t)img * KSEL + fp] = box;
  sscores[(size_t)img * KSEL + fp] = __uint_as_float(u);
}

// ============ Kernel 5: IoU mask build — 128x256 tile per block + diag/ndiag ============
// diag[i]  = row i's word chunk(i)     (intra-chunk kills)
// ndiag[i] = row i's word chunk(i)+1   (next-chunk kills, for the lagged sweep)
// v12 = v7/v10 (R10 best-known, 129 us): register-distributed select epilogue,
//   uniform scalar masks, speculation-protected fallback. (R13's transposed
//   batch variant reverted: VGPR 84 / occupancy 23% / 149 us.)
__global__ __launch_bounds__(256) void mask_build_kernel(const float4* __restrict__ sboxes,
                                                         ull* __restrict__ mask,
                                                         ull* __restrict__ diag,
                                                         ull* __restrict__ ndiag) {
#pragma clang fp contract(off)
  const int jt = blockIdx.x;       // 0..19  (column tile of 256)
  const int sp = blockIdx.y;       // 0..39  (strip pair: strips 2sp, 2sp+1)
  const int img = blockIdx.z;
  if (jt < (sp >> 1)) return;      // fully below both strips
  const int tid = threadIdx.x;
  const int lane = tid & 63;
  // wave index is wave-uniform by construction; readfirstlane makes it
  // PROVABLY uniform to the compiler (scalar branches, scalar masks below).
  const int wave = __builtin_amdgcn_readfirstlane(tid >> 6);
  __shared__ float4 ib[128];
  const float4* bb = sboxes + (size_t)img * KSEL;
  if (tid < 128) {
    int i = sp * 128 + tid;
    ib[tid] = (i < KSEL) ? bb[i] : make_float4(0.f, 0.f, 0.f, 0.f);
  }
  __syncthreads();
  float4 cb[4];
  float ca[4];
#pragma unroll
  for (int s = 0; s < 4; ++s) {
    int j = jt * 256 + s * 64 + lane;
    cb[s] = (j < KSEL) ? bb[j] : make_float4(0.f, 0.f, 0.f, 0.f);
    ca[s] = (cb[s].z - cb[s].x) * (cb[s].w - cb[s].y);
  }
  const int grp0 = jt * 4;
  const int strip = 2 * sp + (wave >> 1);  // uniform
  const int sd = strip - grp0;             // diag group index if in [0,4)
  const int i0 = sp * 128 + wave * 32;
  const int rbase = (wave & 1) * 32;       // row offset within the 64-chunk
  const bool needD = (sd >= 0 && sd < 4);  // uniform
  const bool needN = (sd >= -1 && sd < 3); // ndiag group sd+1 in this tile

  if (i0 < KSEL) {
    uint a0 = 0, a1 = 0, a2 = 0, a3 = 0;       // mask accumulators
    uint dgl = 0, dgh = 0, ngl = 0, ngh = 0;   // diag / next-diag collects

#pragma unroll 4
    for (int k = 0; k < 32; ++k) {
      const float4 pb = ib[wave * 32 + k];
      const float pa = (pb.z - pb.x) * (pb.w - pb.y);
      ull w0 = kill_mask(pb, pa, cb[0], ca[0]);
      ull w1 = kill_mask(pb, pa, cb[1], ca[1]);
      ull w2 = kill_mask(pb, pa, cb[2], ca[2]);
      ull w3 = kill_mask(pb, pa, cb[3], ca[3]);
      if (needD) {                           // uniform (scalar) branch
        const ull gtm = 0xFFFFFFFFFFFFFFFEULL << (rbase + k);  // bits r+1..63
        ull wd;
        if (sd == 0)      { w0 &= gtm; wd = w0; }
        else if (sd == 1) { w1 &= gtm; wd = w1; }
        else if (sd == 2) { w2 &= gtm; wd = w2; }
        else              { w3 &= gtm; wd = w3; }
        const bool ck = (lane == k);
        dgl = ck ? (uint)wd : dgl;
        dgh = ck ? (uint)(wd >> 32) : dgh;
      }
      if (needN) {                           // uniform (scalar) branch
        ull wn;
        if (sd == -1)     wn = w0;
        else if (sd == 0) wn = w1;
        else if (sd == 1) wn = w2;
        else              wn = w3;
        const bool ck = (lane == k);
        ngl = ck ? (uint)wn : ngl;
        ngh = ck ? (uint)(wn >> 32) : ngh;
      }
      // accumulate: even lane 2k holds row k's bytes 0..15 {w0,w1},
      //             odd  lane 2k+1 holds bytes 16..31 {w2,w3}
      const bool c0 = (lane == 2 * k);
      const bool c1 = (lane == 2 * k + 1);
      a0 = c0 ? (uint)w0 : a0;         a0 = c1 ? (uint)w2 : a0;
      a1 = c0 ? (uint)(w0 >> 32) : a1; a1 = c1 ? (uint)(w2 >> 32) : a1;
      a2 = c0 ? (uint)w1 : a2;         a2 = c1 ? (uint)w3 : a2;
      a3 = c0 ? (uint)(w1 >> 32) : a3; a3 = c1 ? (uint)(w3 >> 32) : a3;
    }

    // flush: lane l holds 16B for row i0 + l/2, half (l&1)
    ull* mrow = mask + (size_t)img * KSEL * MW;
    const int row = i0 + (lane >> 1);
    if (row < KSEL) {
      uint* wp = (uint*)(mrow + (size_t)row * MW + grp0) + (lane & 1) * 4;
      *(uint4*)wp = make_uint4(a0, a1, a2, a3);
    }
    const int drow = i0 + lane;
    if (needD && lane < 32 && drow < KSEL)
      diag[(size_t)img * KSELP + drow] = ((ull)dgh << 32) | dgl;
    if (needN && lane < 32 && drow < KSEL)
      ndiag[(size_t)img * KSELP + drow] = ((ull)ngh << 32) | ngl;
  }
}

// ============ Kernel 6: sweep — producer/consumer wave pair ============
// v12 = v10 (R10 best-known scalarized walker) + full-output epilogue:
//   each block writes its image's ENTIRE out slab (class-0 zeros, class-1
//   picks, class-1 tail zeros), removing the host-side memset(d_out)
//   dispatch. Walk/protocol identical to R10 (lag-2, scalar s_ff1 chain,
//   mbcnt-ranked pickbuf, 2-deep diag prefetch).
__global__ __launch_bounds__(128) void sweep_kernel(const ull* __restrict__ mask,
                                                    const ull* __restrict__ diag,
                                                    const ull* __restrict__ ndiag,
                                                    const float4* __restrict__ sboxes,
                                                    const float* __restrict__ sscores,
                                                    const int* __restrict__ meta,
                                                    float* __restrict__ out) {
  const int img = blockIdx.x;
  const int tid = threadIdx.x;
  const int lane = tid & 63;
  const bool waveA = (tid < 64);
  const int V = min(meta[img], KSEL);
  const ull* mb = mask + (size_t)img * KSEL * MW;
  const ull* dg = diag + (size_t)img * KSELP;
  const ull* ng = ndiag + (size_t)img * KSELP;
  __shared__ ull mailbox[NCHUNK + 1];
  __shared__ int pickbuf[TOPK];
  __shared__ int s_np[NCHUNK];
  __shared__ int s_start[NCHUNK];
  __shared__ int s_done;
  __shared__ int s_n;
  const int lc = min(lane, 39);  // B: lane-owned remv words {2lc, 2lc+1}

  // zero the WHOLE mailbox: mailbox[0] and mailbox[1] are consumed before
  // wave B's first publish (which is mailbox[2]).
  for (int i = tid; i <= NCHUNK; i += 128) mailbox[i] = 0ULL;
  if (tid == 0) { s_done = 0; s_n = 0; }
  __syncthreads();

  if (V > 0) {
    // wave-private state
    ull dw = 0, ndw = 0, dw1 = 0, ndw1 = 0, bridge = 0;  // A (2-deep prefetch)
    ull rlo = 0, rhi = 0;                                // B
    int nkeep = 0;
    bool adone = false;
    if (waveA) {
      dw = dg[lane]; ndw = ng[lane];
      const int i1 = min(64 + lane, KSELP - 1);
      dw1 = dg[i1]; ndw1 = ng[i1];
    }

    for (int k = 0; k < NCHUNK; ++k) {
      softBarrier();
      if (s_done) break;  // uniform LDS value: both waves break together
      if (waveA) {
        if (!adone) {
          const int base = k * 64;
          // prefetch chunk k+2's diag words (used in 2 steps; own vmcnt)
          const int nidx = min(base + 128 + lane, KSELP - 1);
          ull dw2 = dg[nidx];
          ull ndw2 = ng[nidx];
          // pin chunk state to SGPRs: the whole walk below is scalar
          ull cur = rfl64(mailbox[k] | bridge);
          bridge = 0ULL;
          const int lim = V - base;
          ull validm = (lim >= 64) ? ~0ULL : ((~0ULL) >> (64 - lim));
          ull avail = (~cur) & validm;
          ull picked = 0ULL;
          const int st = nkeep;
          while (avail != 0ULL && nkeep < TOPK) {
            int r = __builtin_ctzll(avail);        // s_ff1 (uniform)
            picked |= (1ULL << r);
            nkeep++;
            ull dr = readlane64(dw, r);            // critical chain
            bridge |= readlane64(ndw, r);          // off-chain
            avail &= ~(dr | (1ULL << r));
          }
          // cooperative ordered pickbuf write: picks ascend within a chunk,
          // lane's rank = popcount(picked below lane) via mbcnt
          {
            uint plo = (uint)picked, phi = (uint)(picked >> 32);
            int rank = (int)__builtin_amdgcn_mbcnt_hi(
                phi, __builtin_amdgcn_mbcnt_lo(plo, 0u));
            if ((picked >> lane) & 1ULL) pickbuf[st + rank] = base + lane;
          }
          if (lane == 0) { s_np[k] = nkeep - st; s_start[k] = st; }
          if (nkeep >= TOPK || base + 64 >= V) {
            if (lane == 0) { s_done = 1; s_n = (nkeep < TOPK) ? nkeep : TOPK; }
            adone = true;
          }
          dw = dw1; ndw = ndw1;
          dw1 = dw2; ndw1 = ndw2;
        }
      } else if (k >= 1) {
        const int np = s_np[k - 1];
        const int st = s_start[k - 1];
        for (int g = 0; g < np; g += 16) {
          ulonglong2 v[16];
#pragma unroll
          for (int q = 0; q < 16; ++q) {
            int t = min(g + q, np - 1);       // clamped duplicates: idempotent OR
            int row = pickbuf[st + t];
            v[q] = *(const ulonglong2*)(mb + (size_t)row * MW + 2 * lc);
          }
#pragma unroll
          for (int q = 0; q < 16; ++q) { rlo |= v[q].x; rhi |= v[q].y; }
        }
        const int w = k + 1;
        if (w < NCHUNK) {
          ull t = (w & 1) ? rhi : rlo;
          ull word = readlane64(t, w >> 1);
          if (lane == 0) mailbox[w] = word;
        }
      }
    }
  }

  __syncthreads();
  const int n = s_n;
  float* obase = out + (size_t)img * (2 * TOPK * 5);
  // class-0 slab: all zeros (replaces host memset of d_out)
  for (int j = tid; j < TOPK * 5; j += 128) obase[j] = 0.f;
  // class-1 tail beyond the n picks: zeros
  for (int j = TOPK * 5 + n * 5 + tid; j < 2 * TOPK * 5; j += 128) obase[j] = 0.f;
  // class-1 picks
  float* ob = obase + TOPK * 5;
  for (int j = tid; j < n; j += 128) {
    int i = pickbuf[j];
    float4 b = sboxes[(size_t)img * KSEL + i];
    float sc = sscores[(size_t)img * KSEL + i];
    float* o = ob + (size_t)j * 5;
    o[0] = sc; o[1] = b.x; o[2] = b.y; o[3] = b.z; o[4] = b.w;
  }
}

extern "C" void kernel_launch(void* const* d_in, const int* in_sizes, int n_in,
                              void* d_out, int out_size, void* d_ws, size_t ws_size,
                              hipStream_t stream) {
  const float* loc = (const float*)d_in[0];    // [16, 131072, 4]
  const float* conf = (const float*)d_in[1];   // [16*131072, 2]
  const float* prior = (const float*)d_in[2];  // [131072, 4]
  float* out = (float*)d_out;                  // [16, 2, 750, 5]

  char* ws = (char*)d_ws;
  ull* pairs = (ull*)(ws + WS_PAIRS);
  ull* ndiag = (ull*)(ws + WS_NDIAG);          // aliases pairs (dead after rank_decode)
  int* meta = (int*)(ws + WS_MCNT);
  float4* sboxes = (float4*)(ws + WS_BOXES);
  float* sscores = (float*)(ws + WS_SCORES);
  ull* mask = (ull*)(ws + WS_MASK);
  ull* diag = (ull*)(ws + WS_DIAG);
  unsigned int* hist = (unsigned int*)(ws + WS_HIST);
  unsigned int* cnt = (unsigned int*)(ws + WS_CNT);
  unsigned int* pos = (unsigned int*)(ws + WS_POS);

  // hist only (4 MB): cnt is zeroed by cutoff_kernel, out by sweep_kernel
  hipMemsetAsync(ws + WS_HIST, 0, 4194304u, stream);

  {
    dim3 g(64, NIMG);
    hist_kernel<<<g, 256, 0, stream>>>(conf, hist);
  }
  cutoff_kernel<<<NIMG, 1024, 0, stream>>>(hist, pos, cnt, meta, sboxes, sscores);
  {
    dim3 g(64, NIMG);
    scatter_kernel<<<g, 256, 0, stream>>>(conf, pos, cnt, meta, pairs);
  }
  {
    dim3 g((SORTN + 255) / 256, NIMG);
    rank_decode_kernel<<<g, 256, 0, stream>>>(pairs, hist, pos, meta, loc, prior, sboxes, sscores);
  }
  {
    dim3 g(20, 40, NIMG);
    mask_build_kernel<<<g, 256, 0, stream>>>(sboxes, mask, diag, ndiag);
  }
  sweep_kernel<<<NIMG, 128, 0, stream>>>(mask, diag, ndiag, sboxes, sscores, meta, out);
}